// Round 2
// baseline (23752.441 us; speedup 1.0000x reference)
//
#include <hip/hip_runtime.h>
#include <math.h>

// HybridQLSTM persistent-kernel implementation.
// T=1024 steps, B=64, D_IN=256, H=256, 4 gates. out = stacked[1024,64,256] ++ hx ++ cx.
//
// Grid: 64 blocks = 4 gates x 16 column-tiles (16 cols), 256 threads (4 waves).
// All weights live in LDS in MFMA B-fragment layout as split-bf16 (hi+lo) pairs.
// 3 device-wide epoch barriers per step (distributed flags, leader-poll).
// Stage1 x-part (no h dependence) runs before the barrier wait to hide latency.

#define TS   1024
#define BB   64
#define HH   256
#define NB   64          // blocks
#define NELEM (BB*HH)    // 16384

typedef __attribute__((ext_vector_type(8))) short bf16x8;   // 8 bf16 in 4 VGPRs
typedef __attribute__((ext_vector_type(4))) float f32x4;

// ---------------- barrier helpers (epoch-based, monotonic) ----------------
__device__ __forceinline__ int ld_flag(const int* p) {
    return __hip_atomic_load(p, __ATOMIC_RELAXED, __HIP_MEMORY_SCOPE_AGENT);
}
__device__ __forceinline__ void st_flag(int* p, int v) {
    __hip_atomic_store(p, v, __ATOMIC_RELEASE, __HIP_MEMORY_SCOPE_AGENT);
}

// arrive: publish this block's writes, mark epoch e. (Leader publishes via rel store.)
__device__ __forceinline__ void bar_arrive(int e, int bid, int tid, int* arr) {
    __syncthreads();                       // all waves' stores drained (vmcnt0 before s_barrier)
    if (bid != 0 && tid == 0) st_flag(&arr[bid * 32], e);
}
// wait: leader polls all arrivals with 63 lanes then releases; others spin on rel.
__device__ __forceinline__ void bar_wait(int e, int bid, int tid, int* arr, int* rel) {
    if (bid == 0) {
        if (tid >= 1 && tid < 64) {
            while (ld_flag(&arr[tid * 32]) < e) __builtin_amdgcn_s_sleep(1);
        }
        __syncthreads();
        if (tid == 0) st_flag(rel, e);     // release: publishes leader writes + transitivity
    } else {
        if (tid == 0) {
            while (ld_flag(rel) < e) __builtin_amdgcn_s_sleep(1);
        }
    }
    __builtin_amdgcn_fence(__ATOMIC_ACQUIRE, "agent");
    __syncthreads();
}

// ---------------- split-bf16 helpers ----------------
__device__ __forceinline__ void cvt8(const float* a, bf16x8& hi, bf16x8& lo) {
#pragma unroll
    for (int i = 0; i < 8; ++i) {
        unsigned u = __builtin_bit_cast(unsigned, a[i]);
        unsigned short h = (unsigned short)(u >> 16);            // truncate to bf16
        float hf = __builtin_bit_cast(float, (unsigned)h << 16);
        float lf = a[i] - hf;                                     // exact residual
        unsigned short l2 = (unsigned short)(__builtin_bit_cast(unsigned, lf) >> 16);
        hi[i] = (short)h;
        lo[i] = (short)l2;
    }
}
__device__ __forceinline__ f32x4 mf3(bf16x8 ah, bf16x8 al, bf16x8 bh, bf16x8 bl, f32x4 acc) {
    acc = __builtin_amdgcn_mfma_f32_16x16x32_bf16(ah, bh, acc, 0, 0, 0);
    acc = __builtin_amdgcn_mfma_f32_16x16x32_bf16(ah, bl, acc, 0, 0, 0);
    acc = __builtin_amdgcn_mfma_f32_16x16x32_bf16(al, bh, acc, 0, 0, 0);
    return acc;
}

// ---------------- init: zero h, c, flags (ws is poisoned 0xAA pre-launch) ----------------
__global__ __launch_bounds__(256) void qinit(float* h, float* c, int* flags) {
    int i = blockIdx.x * 256 + threadIdx.x;       // 64x256 = 16384
    h[i] = 0.0f;
    c[i] = 0.0f;
    if (i < 64 * 32 + 32) flags[i] = 0;           // arr[64 * 32] ++ rel
}

// ---------------- persistent kernel ----------------
__global__ __launch_bounds__(256, 1) void qlstm_persist(
    const float* __restrict__ x,      // [TS, BB, 256]
    const float* __restrict__ W1,     // [4, 512, 256]
    const float* __restrict__ b1,     // [4, 256]
    const float* __restrict__ W2,     // [4, 256, 256]
    const float* __restrict__ b2,     // [4, 256]
    float* __restrict__ out,          // stacked ++ hx ++ cx
    float* __restrict__ h_glob,       // [64, 256]
    float* __restrict__ c_glob,       // [64, 256]
    float* __restrict__ hid_glob,     // [4, 64, 256]
    float* __restrict__ gates_glob,   // [4, 64, 256]
    int* arr, int* rel)
{
    const int tid = threadIdx.x;
    const int bid = blockIdx.x;
    const int g  = bid >> 4;          // gate 0..3
    const int ct = bid & 15;          // column tile 0..15 (16 cols each)

    // LDS: W1 frags [16 ktiles][hi/lo][64 lanes][8 bf16] = 32KB, then W2 [8 ktiles][..] = 16KB
    __shared__ unsigned short smem[24576];

    // ---- one-time: load weights into LDS in B-fragment layout, split-bf16 ----
    {
        const float* W1g = W1 + (size_t)g * 512 * 256;
        const float* W2g = W2 + (size_t)g * 256 * 256;
        for (int w = tid; w < 24 * 64; w += 256) {
            int ktu  = w >> 6;        // 0..23 (16 W1 ktiles then 8 W2 ktiles)
            int lane = w & 63;
            int quad = lane >> 4, n = lane & 15;
            int col = ct * 16 + n;
            const float* src;
            int k0, base;
            if (ktu < 16) { src = W1g; k0 = ktu * 32 + quad * 8;        base = (ktu * 2) * 512; }
            else          { src = W2g; k0 = (ktu - 16) * 32 + quad * 8; base = 16384 + ((ktu - 16) * 2) * 512; }
#pragma unroll
            for (int j = 0; j < 8; ++j) {
                float f = src[(size_t)(k0 + j) * 256 + col];
                unsigned u = __builtin_bit_cast(unsigned, f);
                unsigned short h16 = (unsigned short)(u >> 16);
                float hf = __builtin_bit_cast(float, (unsigned)h16 << 16);
                float lf = f - hf;
                unsigned short l16 = (unsigned short)(__builtin_bit_cast(unsigned, lf) >> 16);
                smem[base + lane * 8 + j]       = h16;   // hi frag
                smem[base + 512 + lane * 8 + j] = l16;   // lo frag
            }
        }
        __syncthreads();
    }

    const int l    = tid & 63;
    const int wave = tid >> 6;
    const int quad = l >> 4;
    const int n15  = l & 15;
    const int brow = wave * 16 + n15;            // A-operand row this lane loads
    const int col  = ct * 16 + n15;              // D column this lane owns
    const int bo   = wave * 16 + quad * 4;       // D row base for this lane
    const float b1v = b1[g * 256 + col];
    const float b2v = b2[g * 256 + col];

    for (int t = 0; t < TS; ++t) {
        f32x4 accE = {0.f, 0.f, 0.f, 0.f};
        f32x4 accO = {0.f, 0.f, 0.f, 0.f};

        // ---- stage1 x-part (kt 0..7): independent of h -> runs before barrier wait ----
        const float* xr = x + ((size_t)t * BB + brow) * 256;
#pragma unroll
        for (int kt = 0; kt < 8; ++kt) {
            float a[8];
            *(float4*)&a[0] = *(const float4*)(xr + kt * 32 + quad * 8);
            *(float4*)&a[4] = *(const float4*)(xr + kt * 32 + quad * 8 + 4);
            bf16x8 ah, al;
            cvt8(a, ah, al);
            bf16x8 bh = *(const bf16x8*)&smem[(kt * 2) * 512 + l * 8];
            bf16x8 bl = *(const bf16x8*)&smem[(kt * 2) * 512 + 512 + l * 8];
            if (kt & 1) accO = mf3(ah, al, bh, bl, accO);
            else        accE = mf3(ah, al, bh, bl, accE);
        }

        bar_wait(3 * t, bid, tid, arr, rel);     // h_glob for step t ready (t=0: trivial)

        // ---- stage1 h-part (kt 8..15) ----
        const float* hr = h_glob + (size_t)brow * 256;
#pragma unroll
        for (int kt = 8; kt < 16; ++kt) {
            float a[8];
            *(float4*)&a[0] = *(const float4*)(hr + (kt - 8) * 32 + quad * 8);
            *(float4*)&a[4] = *(const float4*)(hr + (kt - 8) * 32 + quad * 8 + 4);
            bf16x8 ah, al;
            cvt8(a, ah, al);
            bf16x8 bh = *(const bf16x8*)&smem[(kt * 2) * 512 + l * 8];
            bf16x8 bl = *(const bf16x8*)&smem[(kt * 2) * 512 + 512 + l * 8];
            if (kt & 1) accO = mf3(ah, al, bh, bl, accO);
            else        accE = mf3(ah, al, bh, bl, accE);
        }
        // epilogue: tanh -> hid
#pragma unroll
        for (int r = 0; r < 4; ++r) {
            float v = accE[r] + accO[r] + b1v;
            hid_glob[(size_t)(g * 64 + bo + r) * 256 + col] = tanhf(v);
        }

        bar_arrive(3 * t + 1, bid, tid, arr);
        bar_wait  (3 * t + 1, bid, tid, arr, rel);

        // ---- stage2: gates[g] = sigmoid(hid[g] @ W2[g] + b2) ----
        accE = (f32x4){0.f, 0.f, 0.f, 0.f};
        accO = (f32x4){0.f, 0.f, 0.f, 0.f};
        const float* ar2 = hid_glob + (size_t)(g * 64 + brow) * 256;
#pragma unroll
        for (int kt = 0; kt < 8; ++kt) {
            float a[8];
            *(float4*)&a[0] = *(const float4*)(ar2 + kt * 32 + quad * 8);
            *(float4*)&a[4] = *(const float4*)(ar2 + kt * 32 + quad * 8 + 4);
            bf16x8 ah, al;
            cvt8(a, ah, al);
            bf16x8 bh = *(const bf16x8*)&smem[16384 + (kt * 2) * 512 + l * 8];
            bf16x8 bl = *(const bf16x8*)&smem[16384 + (kt * 2) * 512 + 512 + l * 8];
            if (kt & 1) accO = mf3(ah, al, bh, bl, accO);
            else        accE = mf3(ah, al, bh, bl, accE);
        }
#pragma unroll
        for (int r = 0; r < 4; ++r) {
            float v = accE[r] + accO[r] + b2v;
            gates_glob[(size_t)(g * 64 + bo + r) * 256 + col] = 1.0f / (1.0f + expf(-v));
        }

        bar_arrive(3 * t + 2, bid, tid, arr);
        bar_wait  (3 * t + 2, bid, tid, arr, rel);

        // ---- update: each block owns 256 elements (1 per thread) ----
        {
            int e = bid * 256 + tid;             // [0, 16384)
            float f = gates_glob[e];
            float i = gates_glob[16384 + e];
            float u = gates_glob[32768 + e];
            float o = gates_glob[49152 + e];
            float c = c_glob[e];
            float cn = f * c + i * tanhf(u);
            float hn = o * tanhf(cn);
            c_glob[e] = cn;
            h_glob[e] = hn;
            out[(size_t)t * NELEM + e] = hn;
            if (t == TS - 1) {
                out[(size_t)TS * NELEM + e]         = hn;   // hx
                out[(size_t)TS * NELEM + NELEM + e] = cn;   // cx
            }
        }
        bar_arrive(3 * t + 3, bid, tid, arr);
    }
}

extern "C" void kernel_launch(void* const* d_in, const int* in_sizes, int n_in,
                              void* d_out, int out_size, void* d_ws, size_t ws_size,
                              hipStream_t stream)
{
    const float* x  = (const float*)d_in[0];
    const float* W1 = (const float*)d_in[1];
    const float* b1 = (const float*)d_in[2];
    const float* W2 = (const float*)d_in[3];
    const float* b2 = (const float*)d_in[4];
    float* out = (float*)d_out;

    float* ws_f  = (float*)d_ws;
    float* h     = ws_f;                 // 16384
    float* c     = ws_f + 16384;         // 16384
    float* hid   = ws_f + 32768;         // 65536
    float* gates = ws_f + 98304;         // 65536
    int*   arr   = (int*)(ws_f + 163840);// 64*32 ints, one flag per cacheline
    int*   rel   = arr + 64 * 32;

    qinit<<<64, 256, 0, stream>>>(h, c, arr);
    qlstm_persist<<<NB, 256, 0, stream>>>(x, W1, b1, W2, b2, out, h, c, hid, gates, arr, rel);
}

// Round 3
// 14614.717 us; speedup vs baseline: 1.6252x; 1.6252x over previous
//
#include <hip/hip_runtime.h>
#include <math.h>

// HybridQLSTM persistent kernel, v2 (fence-free).
// T=1024, B=64, D_IN=256, H=256, 4 gates. out = stacked[1024,64,256] ++ hx ++ cx.
//
// 64 blocks = 4 gates x 16 col-tiles (16 cols), 256 threads (4 waves).
// Weights LDS-resident in MFMA B-frag layout, split-bf16 (hi+lo).
// ALL cross-block traffic = relaxed agent-scope atomics (global_* sc1 -> Infinity
// Cache, coherent, NO buffer_inv/buffer_wbl2). 3 symmetric all-poll barriers/step.
// c never crosses blocks: one register per thread for the whole sequence.

#define TS   1024
#define BB   64
#define HH   256
#define NELEM (BB*HH)

typedef __attribute__((ext_vector_type(8))) short bf16x8;
typedef __attribute__((ext_vector_type(4))) float f32x4;
typedef unsigned long long u64;
typedef unsigned int u32;
typedef unsigned short u16;

// ---- relaxed agent-scope (sc1 / IC-coherent) accessors: no cache maintenance ----
__device__ __forceinline__ u64 ld_a8(const u64* p) {
    return __hip_atomic_load(p, __ATOMIC_RELAXED, __HIP_MEMORY_SCOPE_AGENT);
}
__device__ __forceinline__ u32 ld_a4(const u32* p) {
    return __hip_atomic_load(p, __ATOMIC_RELAXED, __HIP_MEMORY_SCOPE_AGENT);
}
__device__ __forceinline__ void st_a4(u32* p, u32 v) {
    __hip_atomic_store(p, v, __ATOMIC_RELAXED, __HIP_MEMORY_SCOPE_AGENT);
}
__device__ __forceinline__ void st_a2(u16* p, u16 v) {
    __hip_atomic_store(p, v, __ATOMIC_RELAXED, __HIP_MEMORY_SCOPE_AGENT);
}

// ---- symmetric all-poll barrier: arrive(e) + wait(all >= e) ----
// __syncthreads() emits s_waitcnt vmcnt(0) per wave -> all sc1 data stores have
// COMPLETED at the IC before tid0's flag store issues. Consumers' data loads are
// control-dependent on the poll -> issued after flag observed. No fences needed.
__device__ __forceinline__ void gbar(int e, int bid, int tid, int* arr) {
    __syncthreads();
    if (tid == 0)
        __hip_atomic_store(&arr[bid * 16], e, __ATOMIC_RELAXED, __HIP_MEMORY_SCOPE_AGENT);
    if (tid < 64) {
        int v;
        do {
            v = __hip_atomic_load(&arr[tid * 16], __ATOMIC_RELAXED, __HIP_MEMORY_SCOPE_AGENT);
        } while (!__all(v >= e));
    }
    __syncthreads();
    asm volatile("" ::: "memory");
}

// ---- split-bf16 helpers ----
__device__ __forceinline__ void cvt8(const float* a, bf16x8& hi, bf16x8& lo) {
#pragma unroll
    for (int i = 0; i < 8; ++i) {
        unsigned u = __builtin_bit_cast(unsigned, a[i]);
        unsigned short h = (unsigned short)(u >> 16);
        float hf = __builtin_bit_cast(float, (unsigned)h << 16);
        float lf = a[i] - hf;
        unsigned short l2 = (unsigned short)(__builtin_bit_cast(unsigned, lf) >> 16);
        hi[i] = (short)h;
        lo[i] = (short)l2;
    }
}
__device__ __forceinline__ f32x4 mf3(bf16x8 ah, bf16x8 al, bf16x8 bh, bf16x8 bl, f32x4 acc) {
    acc = __builtin_amdgcn_mfma_f32_16x16x32_bf16(ah, bh, acc, 0, 0, 0);
    acc = __builtin_amdgcn_mfma_f32_16x16x32_bf16(ah, bl, acc, 0, 0, 0);
    acc = __builtin_amdgcn_mfma_f32_16x16x32_bf16(al, bh, acc, 0, 0, 0);
    return acc;
}
__device__ __forceinline__ f32x4 mf2(bf16x8 ah, bf16x8 bh, bf16x8 bl, f32x4 acc) {
    acc = __builtin_amdgcn_mfma_f32_16x16x32_bf16(ah, bh, acc, 0, 0, 0);
    acc = __builtin_amdgcn_mfma_f32_16x16x32_bf16(ah, bl, acc, 0, 0, 0);
    return acc;
}

// ---- init: zero h (packed) and flags via sc1 stores ----
__global__ __launch_bounds__(256) void qinit(u32* hpack, int* flags) {
    int i = blockIdx.x * 256 + threadIdx.x;   // 64 blocks -> 16384
    st_a4(&hpack[i], 0u);
    if (i < 64 * 16)
        __hip_atomic_store(&flags[i], 0, __ATOMIC_RELAXED, __HIP_MEMORY_SCOPE_AGENT);
}

// ---- persistent kernel ----
__global__ __launch_bounds__(256, 1) void qlstm_persist(
    const float* __restrict__ x,      // [TS, BB, 256]  (normal cached loads: read-only)
    const float* __restrict__ W1,     // [4, 512, 256]
    const float* __restrict__ b1,     // [4, 256]
    const float* __restrict__ W2,     // [4, 256, 256]
    const float* __restrict__ b2,     // [4, 256]
    float* __restrict__ out,          // stacked ++ hx ++ cx (normal cached stores)
    u32* __restrict__ hpack,          // [64*256] packed (bf16hi | bf16lo<<16) of h
    u16* __restrict__ hid_hi,         // [4*64*256] bf16 of hid
    u32* __restrict__ gatesq,         // [4*64*256] f32 bits of gates
    int* __restrict__ arr)            // 64 flags, 64B apart
{
    const int tid = threadIdx.x;
    const int bid = blockIdx.x;
    const int g  = bid >> 4;          // gate
    const int ct = bid & 15;          // column tile (16 cols)

    // LDS: W1 [16 kt][hi/lo][64 lanes][8 bf16] = 32KB, W2 [8 kt][...] = 16KB
    __shared__ unsigned short smem[24576];
    {
        const float* W1g = W1 + (size_t)g * 512 * 256;
        const float* W2g = W2 + (size_t)g * 256 * 256;
        for (int w = tid; w < 24 * 64; w += 256) {
            int ktu  = w >> 6;
            int lane = w & 63;
            int quad = lane >> 4, n = lane & 15;
            int col = ct * 16 + n;
            const float* src;
            int k0, base;
            if (ktu < 16) { src = W1g; k0 = ktu * 32 + quad * 8;        base = (ktu * 2) * 512; }
            else          { src = W2g; k0 = (ktu - 16) * 32 + quad * 8; base = 16384 + ((ktu - 16) * 2) * 512; }
#pragma unroll
            for (int j = 0; j < 8; ++j) {
                float f = src[(size_t)(k0 + j) * 256 + col];
                unsigned u = __builtin_bit_cast(unsigned, f);
                unsigned short h16 = (unsigned short)(u >> 16);
                float hf = __builtin_bit_cast(float, (unsigned)h16 << 16);
                float lf = f - hf;
                unsigned short l16 = (unsigned short)(__builtin_bit_cast(unsigned, lf) >> 16);
                smem[base + lane * 8 + j]       = h16;
                smem[base + 512 + lane * 8 + j] = l16;
            }
        }
        __syncthreads();
    }

    const int l    = tid & 63;
    const int wave = tid >> 6;
    const int quad = l >> 4;
    const int n15  = l & 15;
    const int brow = wave * 16 + n15;            // A-row this lane loads
    const int col  = ct * 16 + n15;              // D column this lane owns
    const int bo   = wave * 16 + quad * 4;       // D row base
    const float b1v = b1[g * 256 + col];
    const float b2v = b2[g * 256 + col];
    const int e_own = bid * 256 + tid;           // update element this thread owns
    float creg = 0.0f;                           // cell state: register-resident forever

    f32x4 accE = {0.f, 0.f, 0.f, 0.f};
    f32x4 accO = {0.f, 0.f, 0.f, 0.f};

    // ---- peeled stage1 x-part for t=0 ----
    {
        const float* xr = x + (size_t)brow * 256;
#pragma unroll
        for (int kt = 0; kt < 8; ++kt) {
            float a[8];
            *(float4*)&a[0] = *(const float4*)(xr + kt * 32 + quad * 8);
            *(float4*)&a[4] = *(const float4*)(xr + kt * 32 + quad * 8 + 4);
            bf16x8 ah, al;
            cvt8(a, ah, al);
            bf16x8 bh = *(const bf16x8*)&smem[(kt * 2) * 512 + l * 8];
            bf16x8 bl = *(const bf16x8*)&smem[(kt * 2) * 512 + 512 + l * 8];
            if (kt & 1) accO = mf3(ah, al, bh, bl, accO);
            else        accE = mf3(ah, al, bh, bl, accE);
        }
    }

    for (int t = 0; t < TS; ++t) {
        gbar(3 * t, bid, tid, arr);          // h(t-1) visible (t=0: trivial)

        // ---- stage1 h-part: A from hpack (sc1), packed (hi|lo<<16) ----
        {
            const u64* hp = (const u64*)(hpack + brow * 256);
#pragma unroll
            for (int kt = 8; kt < 16; ++kt) {
                int k0 = (kt - 8) * 32 + quad * 8;
                bf16x8 ah, al;
#pragma unroll
                for (int q = 0; q < 4; ++q) {
                    u64 v = ld_a8(hp + (k0 >> 1) + q);
                    u32 w0 = (u32)v, w1 = (u32)(v >> 32);
                    ah[q * 2]     = (short)(w0 & 0xffff);
                    al[q * 2]     = (short)(w0 >> 16);
                    ah[q * 2 + 1] = (short)(w1 & 0xffff);
                    al[q * 2 + 1] = (short)(w1 >> 16);
                }
                bf16x8 bh = *(const bf16x8*)&smem[(kt * 2) * 512 + l * 8];
                bf16x8 bl = *(const bf16x8*)&smem[(kt * 2) * 512 + 512 + l * 8];
                if (kt & 1) accO = mf3(ah, al, bh, bl, accO);
                else        accE = mf3(ah, al, bh, bl, accE);
            }
        }
        // epilogue: tanh -> hid (bf16-hi, rounded)
#pragma unroll
        for (int r = 0; r < 4; ++r) {
            float v = tanhf(accE[r] + accO[r] + b1v);
            u32 u = __builtin_bit_cast(u32, v);
            st_a2(&hid_hi[(size_t)(g * 64 + bo + r) * 256 + col], (u16)((u + 0x8000u) >> 16));
        }

        gbar(3 * t + 1, bid, tid, arr);      // hid(t) visible

        // ---- stage2: gates = sigmoid(hid @ W2 + b2); A = bf16 hid (2-product) ----
        {
            f32x4 s2E = {0.f, 0.f, 0.f, 0.f};
            f32x4 s2O = {0.f, 0.f, 0.f, 0.f};
            const u64* hr = (const u64*)(hid_hi + (size_t)(g * 64 + brow) * 256);
#pragma unroll
            for (int kt = 0; kt < 8; ++kt) {
                int k0 = kt * 32 + quad * 8;
                bf16x8 ah;
                u64 v0 = ld_a8(hr + (k0 >> 2));
                u64 v1 = ld_a8(hr + (k0 >> 2) + 1);
#pragma unroll
                for (int q = 0; q < 4; ++q) ah[q]     = (short)((v0 >> (16 * q)) & 0xffff);
#pragma unroll
                for (int q = 0; q < 4; ++q) ah[4 + q] = (short)((v1 >> (16 * q)) & 0xffff);
                bf16x8 bh = *(const bf16x8*)&smem[16384 + (kt * 2) * 512 + l * 8];
                bf16x8 bl = *(const bf16x8*)&smem[16384 + (kt * 2) * 512 + 512 + l * 8];
                if (kt & 1) s2O = mf2(ah, bh, bl, s2O);
                else        s2E = mf2(ah, bh, bl, s2E);
            }
#pragma unroll
            for (int r = 0; r < 4; ++r) {
                float v = 1.0f / (1.0f + expf(-(s2E[r] + s2O[r] + b2v)));
                st_a4(&gatesq[(size_t)(g * 64 + bo + r) * 256 + col], __builtin_bit_cast(u32, v));
            }
        }

        gbar(3 * t + 2, bid, tid, arr);      // gates(t) visible

        // ---- update: this thread's element, c in register ----
        {
            float f = __builtin_bit_cast(float, ld_a4(gatesq + e_own));
            float i = __builtin_bit_cast(float, ld_a4(gatesq + 16384 + e_own));
            float u = __builtin_bit_cast(float, ld_a4(gatesq + 32768 + e_own));
            float o = __builtin_bit_cast(float, ld_a4(gatesq + 49152 + e_own));
            creg = f * creg + i * tanhf(u);
            float hn = o * tanhf(creg);
            // pack h as (bf16hi | bf16lo<<16)
            u32 hu = __builtin_bit_cast(u32, hn);
            u16 h16 = (u16)(hu >> 16);
            float hf = __builtin_bit_cast(float, (u32)h16 << 16);
            float lf = hn - hf;
            u16 l16 = (u16)(__builtin_bit_cast(u32, lf) >> 16);
            st_a4(&hpack[e_own], (u32)h16 | ((u32)l16 << 16));
            out[(size_t)t * NELEM + e_own] = hn;
            if (t == TS - 1) {
                out[(size_t)TS * NELEM + e_own]         = hn;     // hx
                out[(size_t)TS * NELEM + NELEM + e_own] = creg;   // cx
            }
        }

        // ---- stage1 x-part for t+1 (no h dependence): overlaps stragglers ----
        if (t < TS - 1) {
            accE = (f32x4){0.f, 0.f, 0.f, 0.f};
            accO = (f32x4){0.f, 0.f, 0.f, 0.f};
            const float* xr = x + ((size_t)(t + 1) * BB + brow) * 256;
#pragma unroll
            for (int kt = 0; kt < 8; ++kt) {
                float a[8];
                *(float4*)&a[0] = *(const float4*)(xr + kt * 32 + quad * 8);
                *(float4*)&a[4] = *(const float4*)(xr + kt * 32 + quad * 8 + 4);
                bf16x8 ah, al;
                cvt8(a, ah, al);
                bf16x8 bh = *(const bf16x8*)&smem[(kt * 2) * 512 + l * 8];
                bf16x8 bl = *(const bf16x8*)&smem[(kt * 2) * 512 + 512 + l * 8];
                if (kt & 1) accO = mf3(ah, al, bh, bl, accO);
                else        accE = mf3(ah, al, bh, bl, accE);
            }
        }
    }
}

extern "C" void kernel_launch(void* const* d_in, const int* in_sizes, int n_in,
                              void* d_out, int out_size, void* d_ws, size_t ws_size,
                              hipStream_t stream)
{
    const float* x  = (const float*)d_in[0];
    const float* W1 = (const float*)d_in[1];
    const float* b1 = (const float*)d_in[2];
    const float* W2 = (const float*)d_in[3];
    const float* b2 = (const float*)d_in[4];
    float* out = (float*)d_out;

    char* ws = (char*)d_ws;
    u32* hpack  = (u32*)ws;                       // 64 KB
    u16* hid_hi = (u16*)(ws + 65536);             // 128 KB
    u32* gatesq = (u32*)(ws + 65536 + 131072);    // 256 KB
    int* arr    = (int*)(ws + 65536 + 131072 + 262144);  // 4 KB

    qinit<<<64, 256, 0, stream>>>(hpack, arr);
    qlstm_persist<<<64, 256, 0, stream>>>(x, W1, b1, W2, b2, out,
                                          hpack, hid_hi, gatesq, arr);
}

// Round 4
// 13566.112 us; speedup vs baseline: 1.7509x; 1.0773x over previous
//
#include <hip/hip_runtime.h>
#include <math.h>

// HybridQLSTM persistent kernel v3: 16 blocks, f16 MFMA, minimal IC traffic.
// T=1024, B=64, D_IN=256, H=256, 4 gates. out = stacked[1024,64,256] ++ hx ++ cx.
//
// 16 blocks = 4 gates x 4 col-tiles (64 cols), 256 threads (4 waves).
// Weights LDS-resident as f16 in MFMA B-frag layout (96 KB/block).
// Cross-block traffic via relaxed agent-scope atomics (sc1 -> IC, no fences):
//   h: f16 [64,256]=32KB, hid: f16 [4,64,256]=128KB, gates: u16 fixed [4,64,256].
// 3 symmetric all-poll barriers/step (16 flags). c lives in registers.

#define TS    1024
#define NELEM 16384

typedef unsigned long long u64;
typedef unsigned int u32;
typedef unsigned short u16;
typedef _Float16 f16;
typedef __attribute__((ext_vector_type(8))) _Float16 half8;
typedef __attribute__((ext_vector_type(8))) unsigned short ushort8;
typedef __attribute__((ext_vector_type(4))) float f32x4;

// ---- relaxed agent-scope (sc1/IC) accessors ----
__device__ __forceinline__ u64 ld_a8(const u64* p) {
    return __hip_atomic_load(p, __ATOMIC_RELAXED, __HIP_MEMORY_SCOPE_AGENT);
}
__device__ __forceinline__ void st_a8(u64* p, u64 v) {
    __hip_atomic_store(p, v, __ATOMIC_RELAXED, __HIP_MEMORY_SCOPE_AGENT);
}
__device__ __forceinline__ void st_a2(u16* p, u16 v) {
    __hip_atomic_store(p, v, __ATOMIC_RELAXED, __HIP_MEMORY_SCOPE_AGENT);
}

// ---- symmetric all-poll barrier over 16 blocks ----
// Leading __syncthreads drains each wave's sc1 data stores (vmcnt0) before the
// flag store; consumers' loads are control-dependent on the poll.
__device__ __forceinline__ void gbar(int e, int bid, int tid, int* flags) {
    __syncthreads();
    if (tid == 0)
        __hip_atomic_store(&flags[bid * 16], e, __ATOMIC_RELAXED, __HIP_MEMORY_SCOPE_AGENT);
    const int l = tid & 63;
    for (;;) {
        int ok = 1;
        if (l < 16) {
            int v = __hip_atomic_load(&flags[l * 16], __ATOMIC_RELAXED, __HIP_MEMORY_SCOPE_AGENT);
            ok = (v >= e);
        }
        if (__all(ok)) break;
        __builtin_amdgcn_s_sleep(1);
    }
    asm volatile("" ::: "memory");
}

__device__ __forceinline__ half8 h8_from(u64 v0, u64 v1) {
    ushort8 t;
#pragma unroll
    for (int q = 0; q < 4; ++q) {
        t[q]     = (u16)(v0 >> (16 * q));
        t[4 + q] = (u16)(v1 >> (16 * q));
    }
    return __builtin_bit_cast(half8, t);
}

// ---- init: zero h (f16) and flags ----
__global__ __launch_bounds__(256) void qinit(u64* hglob, int* flags) {
    int i = blockIdx.x * 256 + threadIdx.x;   // 16 blocks -> 4096
    st_a8(&hglob[i], 0ull);                   // 4096 u64 = 32 KB of f16 zeros
    if (i < 16 * 16)
        __hip_atomic_store(&flags[i], 0, __ATOMIC_RELAXED, __HIP_MEMORY_SCOPE_AGENT);
}

// ---- persistent kernel ----
__global__ __launch_bounds__(256, 1) void qlstm_persist(
    const float* __restrict__ x,      // [TS, 64, 256] fp32 (normal cached loads)
    const float* __restrict__ W1,     // [4, 512, 256]
    const float* __restrict__ b1,     // [4, 256]
    const float* __restrict__ W2,     // [4, 256, 256]
    const float* __restrict__ b2,     // [4, 256]
    float* __restrict__ out,          // stacked ++ hx ++ cx (normal cached stores)
    u64* __restrict__ hglob,          // [64*256] f16 h, as u64 (4 cols each)
    u16* __restrict__ hidg,           // [4*64*256] f16 hid
    u16* __restrict__ gateq,          // [4*64*256] u16 fixed-point sigma
    int* __restrict__ flags)          // 16 flags, 64 B apart
{
    const int tid = threadIdx.x;
    const int bid = blockIdx.x;
    const int g  = bid >> 2;          // gate 0..3
    const int ct = bid & 3;           // column tile 0..3 (64 cols)

    // LDS: W1 [16 kt][4 nt][64 lanes][8 f16] = 64 KB ; W2 [8 kt][4 nt][...] = 32 KB
    __shared__ f16 w1s[16 * 4 * 512];
    __shared__ f16 w2s[8 * 4 * 512];
    {
        const float* W1g = W1 + (size_t)g * 512 * 256;
        for (int i = tid; i < 16 * 4 * 64; i += 256) {
            int kt = i >> 8, nt = (i >> 6) & 3, lane = i & 63;
            int k0 = kt * 32 + (lane >> 4) * 8;
            int col = ct * 64 + nt * 16 + (lane & 15);
#pragma unroll
            for (int j = 0; j < 8; ++j)
                w1s[((kt * 4 + nt) * 64 + lane) * 8 + j] = (f16)W1g[(size_t)(k0 + j) * 256 + col];
        }
        const float* W2g = W2 + (size_t)g * 256 * 256;
        for (int i = tid; i < 8 * 4 * 64; i += 256) {
            int kt = i >> 8, nt = (i >> 6) & 3, lane = i & 63;
            int k0 = kt * 32 + (lane >> 4) * 8;
            int col = ct * 64 + nt * 16 + (lane & 15);
#pragma unroll
            for (int j = 0; j < 8; ++j)
                w2s[((kt * 4 + nt) * 64 + lane) * 8 + j] = (f16)W2g[(size_t)(k0 + j) * 256 + col];
        }
        __syncthreads();
    }

    const int l    = tid & 63;
    const int w    = tid >> 6;        // wave: owns batch rows w*16 .. w*16+15
    const int quad = l >> 4;
    const int n15  = l & 15;
    const int brow = w * 16 + n15;    // A-operand row this lane loads
    const int bo   = w * 16 + quad * 4;  // C/D row base
    float b1v[4], b2v[4];
#pragma unroll
    for (int nt = 0; nt < 4; ++nt) {
        b1v[nt] = b1[g * 256 + ct * 64 + nt * 16 + n15];
        b2v[nt] = b2[g * 256 + ct * 64 + nt * 16 + n15];
    }
    // update-phase ownership: 4 consecutive cols of one row
    const int e0   = bid * 1024 + tid * 4;       // [0, 16384)
    const int urow = e0 >> 8;
    const int ucol = e0 & 255;
    float creg[4] = {0.f, 0.f, 0.f, 0.f};

    f32x4 acc[4];
#pragma unroll
    for (int nt = 0; nt < 4; ++nt) acc[nt] = (f32x4){0.f, 0.f, 0.f, 0.f};

    // ---- stage1 x-part (kt 0..7), no h dependence; peeled for t=0 ----
    {
        const float* xr = x + (size_t)brow * 256;
#pragma unroll
        for (int kt = 0; kt < 8; ++kt) {
            float a[8];
            *(float4*)&a[0] = *(const float4*)(xr + kt * 32 + quad * 8);
            *(float4*)&a[4] = *(const float4*)(xr + kt * 32 + quad * 8 + 4);
            half8 ah;
#pragma unroll
            for (int j = 0; j < 8; ++j) ah[j] = (f16)a[j];
#pragma unroll
            for (int nt = 0; nt < 4; ++nt)
                acc[nt] = __builtin_amdgcn_mfma_f32_16x16x32_f16(
                    ah, *(const half8*)&w1s[((kt * 4 + nt) * 64 + l) * 8], acc[nt], 0, 0, 0);
        }
    }

    for (int t = 0; t < TS; ++t) {
        // ---- stage1 h-part (kt 8..15): A = h f16 from IC ----
        {
            const u64* hp = hglob + brow * 64;      // row stride 256 f16 = 64 u64
#pragma unroll
            for (int kt = 8; kt < 16; ++kt) {
                int ko = (kt - 8) * 8 + quad * 2;   // u64 index within row
                u64 v0 = ld_a8(hp + ko);
                u64 v1 = ld_a8(hp + ko + 1);
                half8 ah = h8_from(v0, v1);
#pragma unroll
                for (int nt = 0; nt < 4; ++nt)
                    acc[nt] = __builtin_amdgcn_mfma_f32_16x16x32_f16(
                        ah, *(const half8*)&w1s[((kt * 4 + nt) * 64 + l) * 8], acc[nt], 0, 0, 0);
            }
        }
        // epilogue: hid = tanh(acc + b1) -> f16
#pragma unroll
        for (int nt = 0; nt < 4; ++nt)
#pragma unroll
            for (int r = 0; r < 4; ++r) {
                f16 v = (f16)tanhf(acc[nt][r] + b1v[nt]);
                st_a2(&hidg[(size_t)(g * 64 + bo + r) * 256 + ct * 64 + nt * 16 + n15],
                      __builtin_bit_cast(u16, v));
            }

        gbar(3 * t + 1, bid, tid, flags);       // hid(t) visible

        // ---- stage2: gates = sigmoid(hid @ W2 + b2) -> u16 fixed ----
        {
            f32x4 s2[4];
#pragma unroll
            for (int nt = 0; nt < 4; ++nt) s2[nt] = (f32x4){0.f, 0.f, 0.f, 0.f};
            const u64* hr = (const u64*)(hidg + (size_t)(g * 64 + brow) * 256);
#pragma unroll
            for (int kt = 0; kt < 8; ++kt) {
                int ko = kt * 8 + quad * 2;
                u64 v0 = ld_a8(hr + ko);
                u64 v1 = ld_a8(hr + ko + 1);
                half8 ah = h8_from(v0, v1);
#pragma unroll
                for (int nt = 0; nt < 4; ++nt)
                    s2[nt] = __builtin_amdgcn_mfma_f32_16x16x32_f16(
                        ah, *(const half8*)&w2s[((kt * 4 + nt) * 64 + l) * 8], s2[nt], 0, 0, 0);
            }
#pragma unroll
            for (int nt = 0; nt < 4; ++nt)
#pragma unroll
                for (int r = 0; r < 4; ++r) {
                    float sg = 1.0f / (1.0f + expf(-(s2[nt][r] + b2v[nt])));
                    st_a2(&gateq[(size_t)(g * 64 + bo + r) * 256 + ct * 64 + nt * 16 + n15],
                          (u16)(sg * 65535.0f + 0.5f));
                }
        }

        gbar(3 * t + 2, bid, tid, flags);       // gates(t) visible

        // ---- update: 4 elems/thread, c in registers ----
        {
            const u16* gq = gateq + urow * 256 + ucol;
            u64 qf = ld_a8((const u64*)(gq));
            u64 qi = ld_a8((const u64*)(gq + 16384));
            u64 qu = ld_a8((const u64*)(gq + 32768));
            u64 qo = ld_a8((const u64*)(gq + 49152));
            float4 ov;
            u64 hpack = 0;
            const float s = 1.0f / 65535.0f;
#pragma unroll
            for (int k = 0; k < 4; ++k) {
                float f = (float)((qf >> (16 * k)) & 0xffff) * s;
                float i = (float)((qi >> (16 * k)) & 0xffff) * s;
                float u = (float)((qu >> (16 * k)) & 0xffff) * s;
                float o = (float)((qo >> (16 * k)) & 0xffff) * s;
                creg[k] = f * creg[k] + i * tanhf(u);
                float hn = o * tanhf(creg[k]);
                ((float*)&ov)[k] = hn;
                u16 hb = __builtin_bit_cast(u16, (f16)hn);
                hpack |= (u64)hb << (16 * k);
            }
            *(float4*)(out + (size_t)t * NELEM + e0) = ov;
            st_a8(&hglob[e0 >> 2], hpack);
            if (t == TS - 1) {
                *(float4*)(out + (size_t)TS * NELEM + e0) = ov;             // hx
                float4 cv = {creg[0], creg[1], creg[2], creg[3]};
                *(float4*)(out + (size_t)TS * NELEM + NELEM + e0) = cv;     // cx
            }
        }

        // ---- stage1 x-part for t+1 (overlaps barrier stragglers) ----
#pragma unroll
        for (int nt = 0; nt < 4; ++nt) acc[nt] = (f32x4){0.f, 0.f, 0.f, 0.f};
        if (t < TS - 1) {
            const float* xr = x + ((size_t)(t + 1) * 64 + brow) * 256;
#pragma unroll
            for (int kt = 0; kt < 8; ++kt) {
                float a[8];
                *(float4*)&a[0] = *(const float4*)(xr + kt * 32 + quad * 8);
                *(float4*)&a[4] = *(const float4*)(xr + kt * 32 + quad * 8 + 4);
                half8 ah;
#pragma unroll
                for (int j = 0; j < 8; ++j) ah[j] = (f16)a[j];
#pragma unroll
                for (int nt = 0; nt < 4; ++nt)
                    acc[nt] = __builtin_amdgcn_mfma_f32_16x16x32_f16(
                        ah, *(const half8*)&w1s[((kt * 4 + nt) * 64 + l) * 8], acc[nt], 0, 0, 0);
            }
        }

        gbar(3 * t + 3, bid, tid, flags);       // h(t) visible for next step
    }
}

extern "C" void kernel_launch(void* const* d_in, const int* in_sizes, int n_in,
                              void* d_out, int out_size, void* d_ws, size_t ws_size,
                              hipStream_t stream)
{
    const float* x  = (const float*)d_in[0];
    const float* W1 = (const float*)d_in[1];
    const float* b1 = (const float*)d_in[2];
    const float* W2 = (const float*)d_in[3];
    const float* b2 = (const float*)d_in[4];
    float* out = (float*)d_out;

    char* ws = (char*)d_ws;
    u64* hglob = (u64*)ws;                          // 32 KB
    u16* hidg  = (u16*)(ws + 32768);                // 128 KB
    u16* gateq = (u16*)(ws + 32768 + 131072);       // 128 KB
    int* flags = (int*)(ws + 32768 + 131072 + 131072);  // 1 KB

    qinit<<<16, 256, 0, stream>>>(hglob, flags);
    qlstm_persist<<<16, 256, 0, stream>>>(x, W1, b1, W2, b2, out,
                                          hglob, hidg, gateq, flags);
}